// Round 1
// baseline (102.707 us; speedup 1.0000x reference)
//
#include <hip/hip_runtime.h>
#include <hip/hip_bf16.h>

// Problem constants: B=4, N=4096, C=256, H=8 heads, G=4 groups, d=32, n=1024
// M_TOT = B*N = 16384 rows.

typedef __attribute__((ext_vector_type(8))) short bf16x8;  // 8 bf16 (4 VGPRs)
typedef __attribute__((ext_vector_type(4))) float f32x4;

__device__ __forceinline__ unsigned short f2bf(float x){
  __hip_bfloat16 h = __float2bfloat16(x);   // RNE; compiler can fuse pairs to v_cvt_pk_bf16_f32
  return __builtin_bit_cast(unsigned short, h);
}

// softmax done in exp2 domain: fold SCALE * log2(e) into Q at store time
#define QSCALE (0.17677669529663687f * 1.4426950408889634f)

// ---------------------------------------------------------------------------
// Kernel 1: QKV GEMM. A = x gathered by idx (fp32->bf16 at staging),
// B^T = w_qkv (fp32->bf16 at staging). C scattered to per-head Q,K (n-major)
// and V^T (d-major) bf16 buffers. Tile 64x64, K=256 fully staged in LDS.
// grid = (256 M-tiles, 2 N-halves), block = 256 (4 waves, 2x2 of 32x32).
// ---------------------------------------------------------------------------
__global__ __launch_bounds__(256) void qkv_gemm(
    const float* __restrict__ x, const int* __restrict__ idx,
    const float* __restrict__ w_qkv,
    unsigned short* __restrict__ Qb, unsigned short* __restrict__ Kb,
    unsigned short* __restrict__ Vtg)
{
  __shared__ unsigned short Alds[64*256];   // 32 KiB, XOR-swizzled
  __shared__ unsigned short Blds[64*256];   // 32 KiB
  const int tid = threadIdx.x;
  const int m0 = blockIdx.x << 6;
  const int bb = m0 >> 12;          // batch (64 | 1024, uniform per block)
  const int gg = (m0 >> 10) & 3;    // group
  const int j0 = m0 & 4095;         // permuted position base

  // stage A: 64 rows x 256 k, gather rows via idx
  #pragma unroll
  for (int it = 0; it < 8; ++it){
    int c = (it << 8) + tid;             // 2048 chunks of 8 elems
    int row = c >> 5;
    int k8 = (c & 31) << 3;
    int srow = (bb << 12) + idx[j0 + row];
    const float4 f0 = *(const float4*)(x + srow*256 + k8);
    const float4 f1 = *(const float4*)(x + srow*256 + k8 + 4);
    bf16x8 v;
    v[0]=(short)f2bf(f0.x); v[1]=(short)f2bf(f0.y);
    v[2]=(short)f2bf(f0.z); v[3]=(short)f2bf(f0.w);
    v[4]=(short)f2bf(f1.x); v[5]=(short)f2bf(f1.y);
    v[6]=(short)f2bf(f1.z); v[7]=(short)f2bf(f1.w);
    int byt = ((row << 9) + (k8 << 1)) ^ ((row & 7) << 4);
    *(bf16x8*)((char*)Alds + byt) = v;
  }

  const int w  = tid >> 6, lane = tid & 63;
  const int lr = lane & 15, lg = lane >> 4;
  const int wr = w >> 1,  wc = w & 1;

  for (int nt = 0; nt < 6; ++nt){
    const int n0 = blockIdx.y * 384 + nt * 64;
    __syncthreads();     // prev compute done reading Blds (and A visible on nt=0)
    #pragma unroll
    for (int it = 0; it < 8; ++it){
      int c = (it << 8) + tid;
      int row = c >> 5;
      int k8 = (c & 31) << 3;
      const float4 f0 = *(const float4*)(w_qkv + (n0+row)*256 + k8);
      const float4 f1 = *(const float4*)(w_qkv + (n0+row)*256 + k8 + 4);
      bf16x8 v;
      v[0]=(short)f2bf(f0.x); v[1]=(short)f2bf(f0.y);
      v[2]=(short)f2bf(f0.z); v[3]=(short)f2bf(f0.w);
      v[4]=(short)f2bf(f1.x); v[5]=(short)f2bf(f1.y);
      v[6]=(short)f2bf(f1.z); v[7]=(short)f2bf(f1.w);
      int byt = ((row << 9) + (k8 << 1)) ^ ((row & 7) << 4);
      *(bf16x8*)((char*)Blds + byt) = v;
    }
    __syncthreads();

    f32x4 acc[2][2];
    #pragma unroll
    for (int i=0;i<2;++i)
      #pragma unroll
      for (int j=0;j<2;++j)
        acc[i][j] = (f32x4){0.f,0.f,0.f,0.f};

    #pragma unroll
    for (int ks = 0; ks < 8; ++ks){
      bf16x8 af[2], bfr[2];
      int ka = (ks << 5) + (lg << 3);
      #pragma unroll
      for (int i=0;i<2;++i){
        int rowA = (wr << 5) + (i << 4) + lr;
        int bytA = ((rowA << 9) + (ka << 1)) ^ ((rowA & 7) << 4);
        af[i] = *(const bf16x8*)((const char*)Alds + bytA);
        int rowB = (wc << 5) + (i << 4) + lr;
        int bytB = ((rowB << 9) + (ka << 1)) ^ ((rowB & 7) << 4);
        bfr[i] = *(const bf16x8*)((const char*)Blds + bytB);
      }
      #pragma unroll
      for (int i=0;i<2;++i)
        #pragma unroll
        for (int j=0;j<2;++j)
          acc[i][j] = __builtin_amdgcn_mfma_f32_16x16x32_bf16(af[i], bfr[j], acc[i][j], 0, 0, 0);
    }

    // epilogue: D elem (row = lg*4+q, col = lr) per frag
    #pragma unroll
    for (int i=0;i<2;++i){
      int mr0 = m0 + (wr << 5) + (i << 4) + (lg << 2);
      int nl0 = mr0 & 1023;        // position within group-sequence
      #pragma unroll
      for (int j=0;j<2;++j){
        int o = n0 + (wc << 5) + (j << 4) + lr;    // 0..767
        int s = o >> 8, h = (o >> 5) & 7, dd = o & 31;
        int head = ((bb << 2) + gg) * 8 + h;        // 0..127
        if (s == 2){
          // V stored transposed: Vtg[head][dd][n]  (4 consecutive n -> 8B store)
          ushort4 pk;
          pk.x = f2bf(acc[i][j][0]); pk.y = f2bf(acc[i][j][1]);
          pk.z = f2bf(acc[i][j][2]); pk.w = f2bf(acc[i][j][3]);
          *(ushort4*)(Vtg + head*32768 + dd*1024 + nl0) = pk;
        } else {
          unsigned short* dst = (s==0 ? Qb : Kb) + head*32768 + dd;
          float sc = (s==0) ? QSCALE : 1.0f;
          #pragma unroll
          for (int q=0;q<4;++q)
            dst[(nl0+q) << 5] = f2bf(acc[i][j][q] * sc);
        }
      }
    }
  }
}

// ---------------------------------------------------------------------------
// Kernel 2: attention. 1 block = 1 head x 128 q-rows. 8 waves x 16 q-rows.
// Swapped QK^T (mfma(K,Q)) + K-row permutation so S^T frags land directly in
// the PV A-operand layout. V^T staged in swizzled LDS. Online softmax (exp2).
// grid = 128 heads * 8 qblocks = 1024, block = 512.
// ---------------------------------------------------------------------------
__global__ __launch_bounds__(512) void attn_kernel(
    const unsigned short* __restrict__ Qb, const unsigned short* __restrict__ Kb,
    const unsigned short* __restrict__ Vtg, float* __restrict__ operm)
{
  __shared__ unsigned short Vt[32*1024];   // 64 KiB: V^T[dd][m], XOR-swizzled
  const int tid  = threadIdx.x;
  const int head = blockIdx.x >> 3;
  const int qblk = blockIdx.x & 7;

  const unsigned short* vsrc = Vtg + head*32768;
  #pragma unroll
  for (int it = 0; it < 8; ++it){
    int c  = (it << 9) + tid;        // 4096 chunks of 8 elems
    int dd = c >> 7;
    int ms = c & 127;
    bf16x8 v = *(const bf16x8*)(vsrc + dd*1024 + (ms << 3));
    int byt = ((dd << 11) + (ms << 4)) ^ ((dd & 7) << 4);
    *(bf16x8*)((char*)Vt + byt) = v;
  }
  __syncthreads();

  const int w  = tid >> 6, lane = tid & 63;
  const int lr = lane & 15, lg = lane >> 4;
  const int q0 = qblk * 128 + w * 16;

  const unsigned short* qbase = Qb + head*32768;
  const unsigned short* kbase = Kb + head*32768;
  bf16x8 qf = *(const bf16x8*)(qbase + (q0 + lr)*32 + (lg << 3));  // Q row, hoisted
  const int kperm = ((lr >> 2) << 3) + (lr & 3);  // K-row permutation

  f32x4 o0 = {0.f,0.f,0.f,0.f}, o1 = {0.f,0.f,0.f,0.f};
  float mrun = -1e30f, lrun = 0.f;

  for (int m0 = 0; m0 < 1024; m0 += 32){
    bf16x8 kA = *(const bf16x8*)(kbase + (m0 + kperm    )*32 + (lg << 3));
    bf16x8 kB = *(const bf16x8*)(kbase + (m0 + kperm + 4)*32 + (lg << 3));
    f32x4 z = {0.f,0.f,0.f,0.f};
    f32x4 sA = __builtin_amdgcn_mfma_f32_16x16x32_bf16(kA, qf, z, 0, 0, 0);
    f32x4 sB = __builtin_amdgcn_mfma_f32_16x16x32_bf16(kB, qf, z, 0, 0, 0);
    // lane holds scores of q-row (lr) vs m = m0 + lg*8 + {0..7}
    float p0=sA[0], p1=sA[1], p2=sA[2], p3=sA[3];
    float p4=sB[0], p5=sB[1], p6=sB[2], p7=sB[3];
    float mt = fmaxf(fmaxf(fmaxf(p0,p1),fmaxf(p2,p3)), fmaxf(fmaxf(p4,p5),fmaxf(p6,p7)));
    mt = fmaxf(mt, __shfl_xor(mt, 16));
    mt = fmaxf(mt, __shfl_xor(mt, 32));
    float mnew = fmaxf(mrun, mt);
    p0 = exp2f(p0 - mnew); p1 = exp2f(p1 - mnew);
    p2 = exp2f(p2 - mnew); p3 = exp2f(p3 - mnew);
    p4 = exp2f(p4 - mnew); p5 = exp2f(p5 - mnew);
    p6 = exp2f(p6 - mnew); p7 = exp2f(p7 - mnew);
    float ts = ((p0+p1)+(p2+p3)) + ((p4+p5)+(p6+p7));
    ts += __shfl_xor(ts, 16);
    ts += __shfl_xor(ts, 32);
    float alpha = exp2f(mrun - mnew);
    lrun = lrun * alpha + ts;
    mrun = mnew;
    // rescale O (rows lg*4+q): fetch alpha of that q-row from lane (lg*4+q)
    float ra0 = __shfl(alpha, (lg << 2) + 0);
    float ra1 = __shfl(alpha, (lg << 2) + 1);
    float ra2 = __shfl(alpha, (lg << 2) + 2);
    float ra3 = __shfl(alpha, (lg << 2) + 3);
    o0[0]*=ra0; o0[1]*=ra1; o0[2]*=ra2; o0[3]*=ra3;
    o1[0]*=ra0; o1[1]*=ra1; o1[2]*=ra2; o1[3]*=ra3;
    // P already in PV A-operand layout (k = lg*8+j)
    bf16x8 pf;
    pf[0]=(short)f2bf(p0); pf[1]=(short)f2bf(p1);
    pf[2]=(short)f2bf(p2); pf[3]=(short)f2bf(p3);
    pf[4]=(short)f2bf(p4); pf[5]=(short)f2bf(p5);
    pf[6]=(short)f2bf(p6); pf[7]=(short)f2bf(p7);
    int mb = (m0 + (lg << 3)) << 1;   // byte offset along m
    int b0 = ((lr << 11) + mb)        ^ ((lr & 7) << 4);
    int b1 = (((lr + 16) << 11) + mb) ^ ((lr & 7) << 4);
    bf16x8 v0 = *(const bf16x8*)((const char*)Vt + b0);
    bf16x8 v1 = *(const bf16x8*)((const char*)Vt + b1);
    o0 = __builtin_amdgcn_mfma_f32_16x16x32_bf16(pf, v0, o0, 0, 0, 0);
    o1 = __builtin_amdgcn_mfma_f32_16x16x32_bf16(pf, v1, o1, 0, 0, 0);
  }

  float inv = 1.0f / lrun;
  const int bI = head >> 5, gI = (head >> 3) & 3, hI = head & 7;
  float* obase = operm + (bI*4096 + gI*1024 + q0)*256 + hI*32;
  #pragma unroll
  for (int q = 0; q < 4; ++q){
    float rq = __shfl(inv, (lg << 2) + q);
    obase[((lg << 2) + q)*256 + lr]      = o0[q] * rq;
    obase[((lg << 2) + q)*256 + 16 + lr] = o1[q] * rq;
  }
}

// ---------------------------------------------------------------------------
// Kernel 3: projection GEMM + bias + inverse-permutation scatter.
// A = operm (fp32->bf16 at staging), B^T = w_proj. out[b, idx[j], :] = row j.
// grid = (256, 2), block = 256.
// ---------------------------------------------------------------------------
__global__ __launch_bounds__(256) void proj_gemm(
    const float* __restrict__ operm, const float* __restrict__ w_proj,
    const float* __restrict__ b_proj, const int* __restrict__ idx,
    float* __restrict__ out)
{
  __shared__ unsigned short Alds[64*256];
  __shared__ unsigned short Blds[64*256];
  const int tid = threadIdx.x;
  const int m0 = blockIdx.x << 6;
  const int bb = m0 >> 12;

  #pragma unroll
  for (int it = 0; it < 8; ++it){
    int c = (it << 8) + tid;
    int row = c >> 5;
    int k8 = (c & 31) << 3;
    const float4 f0 = *(const float4*)(operm + (m0+row)*256 + k8);
    const float4 f1 = *(const float4*)(operm + (m0+row)*256 + k8 + 4);
    bf16x8 v;
    v[0]=(short)f2bf(f0.x); v[1]=(short)f2bf(f0.y);
    v[2]=(short)f2bf(f0.z); v[3]=(short)f2bf(f0.w);
    v[4]=(short)f2bf(f1.x); v[5]=(short)f2bf(f1.y);
    v[6]=(short)f2bf(f1.z); v[7]=(short)f2bf(f1.w);
    int byt = ((row << 9) + (k8 << 1)) ^ ((row & 7) << 4);
    *(bf16x8*)((char*)Alds + byt) = v;
  }

  const int w  = tid >> 6, lane = tid & 63;
  const int lr = lane & 15, lg = lane >> 4;
  const int wr = w >> 1,  wc = w & 1;

  for (int nt = 0; nt < 2; ++nt){
    const int n0 = blockIdx.y * 128 + nt * 64;
    __syncthreads();
    #pragma unroll
    for (int it = 0; it < 8; ++it){
      int c = (it << 8) + tid;
      int row = c >> 5;
      int k8 = (c & 31) << 3;
      const float4 f0 = *(const float4*)(w_proj + (n0+row)*256 + k8);
      const float4 f1 = *(const float4*)(w_proj + (n0+row)*256 + k8 + 4);
      bf16x8 v;
      v[0]=(short)f2bf(f0.x); v[1]=(short)f2bf(f0.y);
      v[2]=(short)f2bf(f0.z); v[3]=(short)f2bf(f0.w);
      v[4]=(short)f2bf(f1.x); v[5]=(short)f2bf(f1.y);
      v[6]=(short)f2bf(f1.z); v[7]=(short)f2bf(f1.w);
      int byt = ((row << 9) + (k8 << 1)) ^ ((row & 7) << 4);
      *(bf16x8*)((char*)Blds + byt) = v;
    }
    __syncthreads();

    f32x4 acc[2][2];
    #pragma unroll
    for (int i=0;i<2;++i)
      #pragma unroll
      for (int j=0;j<2;++j)
        acc[i][j] = (f32x4){0.f,0.f,0.f,0.f};

    #pragma unroll
    for (int ks = 0; ks < 8; ++ks){
      bf16x8 af[2], bfr[2];
      int ka = (ks << 5) + (lg << 3);
      #pragma unroll
      for (int i=0;i<2;++i){
        int rowA = (wr << 5) + (i << 4) + lr;
        int bytA = ((rowA << 9) + (ka << 1)) ^ ((rowA & 7) << 4);
        af[i] = *(const bf16x8*)((const char*)Alds + bytA);
        int rowB = (wc << 5) + (i << 4) + lr;
        int bytB = ((rowB << 9) + (ka << 1)) ^ ((rowB & 7) << 4);
        bfr[i] = *(const bf16x8*)((const char*)Blds + bytB);
      }
      #pragma unroll
      for (int i=0;i<2;++i)
        #pragma unroll
        for (int j=0;j<2;++j)
          acc[i][j] = __builtin_amdgcn_mfma_f32_16x16x32_bf16(af[i], bfr[j], acc[i][j], 0, 0, 0);
    }

    #pragma unroll
    for (int i=0;i<2;++i){
      int mr0 = m0 + (wr << 5) + (i << 4) + (lg << 2);
      int rd[4];
      #pragma unroll
      for (int q=0;q<4;++q)
        rd[q] = (bb << 12) + idx[(mr0 + q) & 4095];   // inverse perm as scatter
      #pragma unroll
      for (int j=0;j<2;++j){
        int o = n0 + (wc << 5) + (j << 4) + lr;
        float bias = b_proj[o];
        #pragma unroll
        for (int q=0;q<4;++q)
          out[rd[q]*256 + o] = acc[i][j][q] + bias;
      }
    }
  }
}

// ---------------------------------------------------------------------------
extern "C" void kernel_launch(void* const* d_in, const int* in_sizes, int n_in,
                              void* d_out, int out_size, void* d_ws, size_t ws_size,
                              hipStream_t stream)
{
  const float* x      = (const float*)d_in[0];
  const int*   idx    = (const int*)  d_in[1];
  const float* w_qkv  = (const float*)d_in[2];
  const float* w_proj = (const float*)d_in[3];
  const float* b_proj = (const float*)d_in[4];
  float* out = (float*)d_out;

  char* ws = (char*)d_ws;
  unsigned short* Qb   = (unsigned short*)(ws);                  // 8 MiB
  unsigned short* Kb   = (unsigned short*)(ws + (8u  << 20));    // 8 MiB
  unsigned short* Vtg  = (unsigned short*)(ws + (16u << 20));    // 8 MiB (transposed)
  float*          operm= (float*)        (ws + (24u << 20));     // 16 MiB

  qkv_gemm<<<dim3(256, 2), 256, 0, stream>>>(x, idx, w_qkv, Qb, Kb, Vtg);
  attn_kernel<<<dim3(1024), 512, 0, stream>>>(Qb, Kb, Vtg, operm);
  proj_gemm<<<dim3(256, 2), 256, 0, stream>>>(operm, w_proj, b_proj, idx, out);
}